// Round 1
// baseline (903.796 us; speedup 1.0000x reference)
//
#include <hip/hip_runtime.h>
#include <math.h>

#define B_ 128
#define T_ 8
#define P_ 49
#define H_ 64
#define N_ 343
#define THRESH 0.6f
#define NSLOPE 0.2f

// workspace layout (float offsets)
#define OFF_WM1T 0
#define OFF_WM2T 8192
#define OFF_WG1T 12288
#define OFF_WG2T 16384
#define OFF_SPAT 20480          // B*128 spatial mean accumulator
#define OFF_SPEC 36864          // B*64 spectral mean accumulator
#define OFF_SSRC 45056          // B*N
#define OFF_SDST 88960          // B*N
#define OFF_NODE 132864         // B*N*H
#define OFF_XFN  2942720
#define OFF_XTN  5752576
#define OFF_XW   8562432
#define OFF_OUT1 11372288
// total 14182144 floats = 54.1 MB

__global__ void k_prep(const float* __restrict__ Wm1, const float* __restrict__ Wm2,
                       const float* __restrict__ Wg1, const float* __restrict__ Wg2,
                       float* __restrict__ Wm1T, float* __restrict__ Wm2T,
                       float* __restrict__ Wg1T, float* __restrict__ Wg2T) {
    int t = blockIdx.x * 256 + threadIdx.x;
    if (t < 8192) { int o = t >> 7, i = t & 127; Wm1T[i * 64 + o] = Wm1[t]; }
    if (t < 4096) {
        int r = t >> 6, c = t & 63;
        Wm2T[c * 64 + r] = Wm2[t];   // Wm2T[o][h] = Wm2[h][o]
        Wg1T[c * 64 + r] = Wg1[t];   // Wg1T[h][o] = Wg1[o][h]
        Wg2T[c * 64 + r] = Wg2[t];
    }
}

// one wave per (b,n): node MLP + normalized Xf/Xt rows
__global__ __launch_bounds__(256) void k_node(
    const float* __restrict__ reps, const float* __restrict__ Wm1T, const float* __restrict__ bm1,
    const float* __restrict__ Wm2T, const float* __restrict__ bm2,
    float* __restrict__ node, float* __restrict__ Xfn, float* __restrict__ Xtn)
{
    __shared__ float cat[4][128];
    __shared__ float h1s[4][64];
    int wv = threadIdx.x >> 6, ln = threadIdx.x & 63;
    int idx = blockIdx.x * 4 + wv;            // grid covers B*N exactly
    int b = idx / N_, n = idx - b * N_;
    int f = n / P_, p = n - f * P_;
    const float* xf = reps + (((size_t)b * T_ + f) * P_ + p) * H_;
    float vf = xf[ln], vt = xf[P_ * H_ + ln];
    cat[wv][ln] = vf; cat[wv][64 + ln] = vt;
    float nf = vf * vf, nt = vt * vt;
#pragma unroll
    for (int s = 1; s < 64; s <<= 1) { nf += __shfl_xor(nf, s); nt += __shfl_xor(nt, s); }
    nf = sqrtf(nf) + 1e-4f; nt = sqrtf(nt) + 1e-4f;
    size_t row = (size_t)idx * H_;
    Xfn[row + ln] = vf / nf;
    Xtn[row + ln] = vt / nt;
    __syncthreads();
    float a = bm1[ln];
#pragma unroll 8
    for (int i = 0; i < 128; i++) a += cat[wv][i] * Wm1T[i * 64 + ln];
    h1s[wv][ln] = fmaxf(a, 0.f);
    __syncthreads();
    float nd = bm2[ln];
#pragma unroll 8
    for (int o = 0; o < 64; o++) nd += h1s[wv][o] * Wm2T[o * 64 + ln];
    node[row + ln] = nd;
}

// thread-per-row: S row (max of two cosine sims, thresholded) -> agg -> spectral MLP -> mean accum
__global__ __launch_bounds__(192, 2) void k_spec(
    const float* __restrict__ Xfn, const float* __restrict__ Xtn, const float* __restrict__ node,
    const float* __restrict__ Ws1, const float* __restrict__ bs1,
    const float* __restrict__ Ws2, const float* __restrict__ bs2,
    float* __restrict__ spectral)
{
    __shared__ __align__(16) float sh[12288];   // Xf chunk | Xt chunk | node chunk (64 rows x 64)
    int tid = threadIdx.x;
    int b = blockIdx.x >> 1, half = blockIdx.x & 1;
    int i = half * 172 + tid;
    bool valid = (tid < 172) && (i < N_);
    const float* xfb = Xfn + (size_t)b * N_ * H_;
    const float* xtb = Xtn + (size_t)b * N_ * H_;
    const float* ndb = node + (size_t)b * N_ * H_;
    int ri = valid ? i : 0;
    float xfi[64], xti[64], agg[64];
#pragma unroll
    for (int q = 0; q < 16; q++) {
        float4 a = ((const float4*)(xfb + (size_t)ri * 64))[q];
        float4 c = ((const float4*)(xtb + (size_t)ri * 64))[q];
        xfi[4*q] = a.x; xfi[4*q+1] = a.y; xfi[4*q+2] = a.z; xfi[4*q+3] = a.w;
        xti[4*q] = c.x; xti[4*q+1] = c.y; xti[4*q+2] = c.z; xti[4*q+3] = c.w;
    }
#pragma unroll
    for (int h = 0; h < 64; h++) agg[h] = 0.f;

    for (int c = 0; c < 6; c++) {
        int j0 = c * 64, cnt = min(64, N_ - j0);
        __syncthreads();
        for (int t = tid; t < cnt * 16; t += 192) {
            ((float4*)sh)[t]          = ((const float4*)(xfb + (size_t)j0 * 64))[t];
            ((float4*)(sh + 4096))[t] = ((const float4*)(xtb + (size_t)j0 * 64))[t];
            ((float4*)(sh + 8192))[t] = ((const float4*)(ndb + (size_t)j0 * 64))[t];
        }
        __syncthreads();
        for (int jl = 0; jl < cnt; jl++) {
            const float* xfj = sh + jl * 64;
            const float* xtj = sh + 4096 + jl * 64;
            float sf = 0.f, st = 0.f;
#pragma unroll
            for (int h = 0; h < 64; h++) { sf += xfi[h] * xfj[h]; st += xti[h] * xtj[h]; }
            float s = fmaxf(sf, st);
            if (s > THRESH) {
                const float* ndj = sh + 8192 + jl * 64;
#pragma unroll
                for (int h = 0; h < 64; h++) agg[h] += s * ndj[h];
            }
        }
    }
    // spectral MLP per row (weights read uniformly -> scalar loads)
    float h1v[64];
#pragma unroll
    for (int o = 0; o < 64; o++) {
        float a = bs1[o];
#pragma unroll
        for (int h = 0; h < 64; h++) a += Ws1[o * 64 + h] * agg[h];
        h1v[o] = fmaxf(a, 0.f);
    }
    int ln = tid & 63;
#pragma unroll
    for (int h = 0; h < 64; h++) {
        float a = bs2[h];
#pragma unroll
        for (int o = 0; o < 64; o++) a += Ws2[h * 64 + o] * h1v[o];
        if (!valid) a = 0.f;
#pragma unroll
        for (int s2 = 1; s2 < 64; s2 <<= 1) a += __shfl_xor(a, s2);
        if (ln == 0) atomicAdd(&spectral[b * 64 + h], a);
    }
}

// one wave per (b,n): xw = x @ WgT, plus attention scalars
__global__ __launch_bounds__(256) void k_xw(
    const float* __restrict__ x, const float* __restrict__ WgT,
    const float* __restrict__ as_, const float* __restrict__ ad_,
    float* __restrict__ xw, float* __restrict__ ssrc, float* __restrict__ sdst)
{
    __shared__ float xs[4][64];
    int wv = threadIdx.x >> 6, ln = threadIdx.x & 63;
    int idx = blockIdx.x * 4 + wv;
    size_t row = (size_t)idx * H_;
    xs[wv][ln] = x[row + ln];
    __syncthreads();
    float a = 0.f;
#pragma unroll 8
    for (int h = 0; h < 64; h++) a += xs[wv][h] * WgT[h * 64 + ln];
    xw[row + ln] = a;
    float ps = a * as_[ln], pd = a * ad_[ln];
#pragma unroll
    for (int s = 1; s < 64; s <<= 1) { ps += __shfl_xor(ps, s); pd += __shfl_xor(pd, s); }
    if (ln == 0) { ssrc[idx] = ps; sdst[idx] = pd; }
}

// thread-per-row GAT: online softmax-weighted aggregation + head mix + l2norm + relu
template <int STORE>
__global__ __launch_bounds__(192, 2) void k_gat(
    const float* __restrict__ xw, const float* __restrict__ ssrc, const float* __restrict__ sdst,
    const float* __restrict__ bg, const float* __restrict__ hw, const float* __restrict__ hb,
    float* __restrict__ outrows, float* __restrict__ spatial, int soff)
{
    __shared__ __align__(16) float shw[4096];
    __shared__ float shs[64];
    __shared__ float red[192];
    int tid = threadIdx.x;
    int b = blockIdx.x >> 1, half = blockIdx.x & 1;
    int i = half * 172 + tid;
    bool valid = (tid < 172) && (i < N_);
    const float* xwb = xw + (size_t)b * N_ * H_;
    // max over s_src for this batch
    float m = -1e30f;
    for (int j = tid; j < N_; j += 192) m = fmaxf(m, ssrc[b * N_ + j]);
    red[tid] = m; __syncthreads();
    if (tid < 96) red[tid] = fmaxf(red[tid], red[tid + 96]); __syncthreads();
    if (tid < 48) red[tid] = fmaxf(red[tid], red[tid + 48]); __syncthreads();
    if (tid < 24) red[tid] = fmaxf(red[tid], red[tid + 24]); __syncthreads();
    if (tid < 12) red[tid] = fmaxf(red[tid], red[tid + 12]); __syncthreads();
    if (tid < 6)  red[tid] = fmaxf(red[tid], red[tid + 6]);  __syncthreads();
    if (tid < 3)  red[tid] = fmaxf(red[tid], red[tid + 3]);  __syncthreads();
    if (tid == 0) red[0] = fmaxf(fmaxf(red[0], red[1]), red[2]);
    __syncthreads();
    float maxs = red[0];

    float di = valid ? sdst[b * N_ + i] : 0.f;
    float Mi = di + maxs; Mi = (Mi >= 0.f) ? Mi : NSLOPE * Mi;
    float acc[64]; float den = 0.f;
#pragma unroll
    for (int h = 0; h < 64; h++) acc[h] = 0.f;

    for (int c = 0; c < 6; c++) {
        int j0 = c * 64, cnt = min(64, N_ - j0);
        __syncthreads();
        for (int t = tid; t < cnt * 16; t += 192)
            ((float4*)shw)[t] = ((const float4*)(xwb + (size_t)j0 * 64))[t];
        if (tid < cnt) shs[tid] = ssrc[b * N_ + j0 + tid];
        __syncthreads();
        for (int jl = 0; jl < cnt; jl++) {
            float l = di + shs[jl]; l = (l >= 0.f) ? l : NSLOPE * l;
            float w = __expf(l - Mi);
            den += w;
            const float* xj = shw + jl * 64;
#pragma unroll
            for (int h = 0; h < 64; h++) acc[h] += w * xj[h];
        }
    }
    float inv = 1.f / den;
    float g[64];
#pragma unroll
    for (int h = 0; h < 64; h++) g[h] = acc[h] * inv + bg[h];
    // head mix: y[k,e] = sum_d g[k*16+d]*hw[k][e][d] + hb[k][e]
    float y[64]; float ss = 0.f;
#pragma unroll
    for (int k = 0; k < 4; k++)
#pragma unroll
        for (int e = 0; e < 16; e++) {
            float a = hb[k * 16 + e];
#pragma unroll
            for (int d = 0; d < 16; d++) a += g[k * 16 + d] * hw[(k * 16 + e) * 16 + d];
            y[k * 16 + e] = a; ss += a * a;
        }
    float r = 1.f / fmaxf(sqrtf(ss), 1e-12f);
#pragma unroll
    for (int h = 0; h < 64; h++) y[h] = fmaxf(y[h] * r, 0.f);
    if (STORE && valid) {
        float* orow = outrows + (size_t)(b * N_ + i) * H_;
#pragma unroll
        for (int q = 0; q < 16; q++)
            ((float4*)orow)[q] = make_float4(y[4*q], y[4*q+1], y[4*q+2], y[4*q+3]);
    }
    int ln = tid & 63;
#pragma unroll
    for (int h = 0; h < 64; h++) {
        float a = valid ? y[h] : 0.f;
#pragma unroll
        for (int s2 = 1; s2 < 64; s2 <<= 1) a += __shfl_xor(a, s2);
        if (ln == 0) atomicAdd(&spatial[b * 128 + soff + h], a);
    }
}

__global__ void k_final(const float* __restrict__ spatial, const float* __restrict__ spectral,
                        const float* __restrict__ Wf, const float* __restrict__ bf_,
                        float* __restrict__ out)
{
    int b = blockIdx.x, ln = threadIdx.x;  // 64 threads
    float inv = 1.f / (float)N_;
    float e0 = spatial[b * 128 + ln] * inv;
    float e1 = spatial[b * 128 + 64 + ln] * inv;
    float e2 = spectral[b * 64 + ln] * inv;
#pragma unroll
    for (int c = 0; c < 2; c++) {
        float a = e0 * Wf[c * 192 + ln] + e1 * Wf[c * 192 + 64 + ln] + e2 * Wf[c * 192 + 128 + ln];
#pragma unroll
        for (int s = 1; s < 64; s <<= 1) a += __shfl_xor(a, s);
        if (ln == 0) out[b * 2 + c] = a + bf_[c];
    }
}

extern "C" void kernel_launch(void* const* d_in, const int* in_sizes, int n_in,
                              void* d_out, int out_size, void* d_ws, size_t ws_size,
                              hipStream_t stream)
{
    const float* reps = (const float*)d_in[0];
    const float* Wm1  = (const float*)d_in[1];
    const float* bm1  = (const float*)d_in[2];
    const float* Wm2  = (const float*)d_in[3];
    const float* bm2  = (const float*)d_in[4];
    const float* Wg1  = (const float*)d_in[5];
    const float* a1s  = (const float*)d_in[6];
    const float* a1d  = (const float*)d_in[7];
    const float* bg1  = (const float*)d_in[8];
    const float* hw1  = (const float*)d_in[9];
    const float* hb1  = (const float*)d_in[10];
    const float* Wg2  = (const float*)d_in[11];
    const float* a2s  = (const float*)d_in[12];
    const float* a2d  = (const float*)d_in[13];
    const float* bg2  = (const float*)d_in[14];
    const float* hw3  = (const float*)d_in[15];
    const float* hb3  = (const float*)d_in[16];
    const float* Ws1  = (const float*)d_in[17];
    const float* bs1  = (const float*)d_in[18];
    const float* Ws2  = (const float*)d_in[19];
    const float* bs2  = (const float*)d_in[20];
    const float* Wf   = (const float*)d_in[21];
    const float* bf_  = (const float*)d_in[22];

    float* ws = (float*)d_ws;
    float* Wm1T = ws + OFF_WM1T;
    float* Wm2T = ws + OFF_WM2T;
    float* Wg1T = ws + OFF_WG1T;
    float* Wg2T = ws + OFF_WG2T;
    float* spat = ws + OFF_SPAT;
    float* spec = ws + OFF_SPEC;
    float* ssrc = ws + OFF_SSRC;
    float* sdst = ws + OFF_SDST;
    float* node = ws + OFF_NODE;
    float* Xfn  = ws + OFF_XFN;
    float* Xtn  = ws + OFF_XTN;
    float* xwb  = ws + OFF_XW;
    float* out1 = ws + OFF_OUT1;

    hipMemsetAsync(spat, 0, (16384 + 8192) * sizeof(float), stream);
    k_prep<<<32, 256, 0, stream>>>(Wm1, Wm2, Wg1, Wg2, Wm1T, Wm2T, Wg1T, Wg2T);
    k_node<<<(B_ * N_) / 4, 256, 0, stream>>>(reps, Wm1T, bm1, Wm2T, bm2, node, Xfn, Xtn);
    k_spec<<<B_ * 2, 192, 0, stream>>>(Xfn, Xtn, node, Ws1, bs1, Ws2, bs2, spec);
    k_xw<<<(B_ * N_) / 4, 256, 0, stream>>>(node, Wg1T, a1s, a1d, xwb, ssrc, sdst);
    k_gat<1><<<B_ * 2, 192, 0, stream>>>(xwb, ssrc, sdst, bg1, hw1, hb1, out1, spat, 0);
    k_xw<<<(B_ * N_) / 4, 256, 0, stream>>>(out1, Wg2T, a2s, a2d, xwb, ssrc, sdst);
    k_gat<0><<<B_ * 2, 192, 0, stream>>>(xwb, ssrc, sdst, bg2, hw3, hb3, nullptr, spat, 64);
    k_final<<<B_, 64, 0, stream>>>(spat, spec, Wf, bf_, (float*)d_out);
}